// Round 2
// baseline (488.074 us; speedup 1.0000x reference)
//
#include <hip/hip_runtime.h>

#define B_ 8
#define C_ 256
#define H_ 128
#define W_ 128
#define NW_ 512
#define HW_ (H_*W_)
#define EPS_ 1e-5f

typedef __attribute__((ext_vector_type(8))) short bf16x8;
typedef __attribute__((ext_vector_type(4))) float f32x4;

// RNE float -> bf16
__device__ __forceinline__ unsigned short f2bf(float f) {
  unsigned u = __float_as_uint(f);
  u += 0x7fffu + ((u >> 16) & 1u);
  return (unsigned short)(u >> 16);
}
__device__ __forceinline__ float bf2f(unsigned short h) {
  return __uint_as_float(((unsigned)h) << 16);
}
__device__ __forceinline__ float bflo(unsigned u) { return __uint_as_float(u << 16); }
__device__ __forceinline__ float bfhi(unsigned u) { return __uint_as_float(u & 0xffff0000u); }

// ---------- BN stats, two-stage ----------
__global__ __launch_bounds__(256)
void bn_partial(const float* __restrict__ x, float* __restrict__ psum,
                float* __restrict__ psq) {
  const int b = blockIdx.x, c = blockIdx.y, tid = threadIdx.x;
  const float4* p = (const float4*)(x + (size_t)(b*C_ + c) * HW_);
  float s = 0.f, s2 = 0.f;
  #pragma unroll
  for (int i = 0; i < 16; ++i) {
    float4 v = p[tid + i*256];
    s  += v.x + v.y + v.z + v.w;
    s2 += v.x*v.x + v.y*v.y + v.z*v.z + v.w*v.w;
  }
  #pragma unroll
  for (int off = 32; off > 0; off >>= 1) {
    s  += __shfl_down(s, off);
    s2 += __shfl_down(s2, off);
  }
  __shared__ float rs[4], rq[4];
  if ((tid & 63) == 0) { rs[tid >> 6] = s; rq[tid >> 6] = s2; }
  __syncthreads();
  if (tid == 0) {
    float S = rs[0]+rs[1]+rs[2]+rs[3], S2 = rq[0]+rq[1]+rq[2]+rq[3];
    psum[c*B_ + b] = S;
    psq [c*B_ + b] = S2;
  }
}

__global__ __launch_bounds__(256)
void bn_final(float* __restrict__ wsf, const float* __restrict__ gamma,
              const float* __restrict__ beta) {
  const int c = threadIdx.x;
  float S = 0.f, S2 = 0.f;
  #pragma unroll
  for (int b = 0; b < B_; ++b) { S += wsf[512 + c*B_ + b]; S2 += wsf[2560 + c*B_ + b]; }
  const float n = (float)(B_*HW_);
  float mean = S / n;
  float var  = S2 / n - mean*mean;
  float scl  = gamma[c] * rsqrtf(var + EPS_);
  wsf[c]       = scl;
  wsf[C_ + c]  = beta[c] - mean*scl;
}

// ---------- w1 -> bf16 A-fragment table ----------
__global__ __launch_bounds__(64)
void w1prep(const float* __restrict__ w1, ushort* __restrict__ w1f) {
  const int l15 = threadIdx.x & 15, quad = threadIdx.x >> 4;
  const int mtG = blockIdx.x >> 4, ks = blockIdx.x & 15;
  const float* src = w1 + (size_t)(mtG*16 + l15)*NW_ + ks*32 + quad*8;
  float4 f0 = *(const float4*)src, f1 = *(const float4*)(src + 4);
  union { unsigned u[4]; uint4 q; } cv;
  cv.u[0] = (unsigned)f2bf(f0.x) | ((unsigned)f2bf(f0.y) << 16);
  cv.u[1] = (unsigned)f2bf(f0.z) | ((unsigned)f2bf(f0.w) << 16);
  cv.u[2] = (unsigned)f2bf(f1.x) | ((unsigned)f2bf(f1.y) << 16);
  cv.u[3] = (unsigned)f2bf(f1.z) | ((unsigned)f2bf(f1.w) << 16);
  ((uint4*)w1f)[blockIdx.x*64 + threadIdx.x] = cv.q;
}

// ---------- fused: BN-apply + dw3x3 + relu + 1x1 (MFMA) + bias + residual ----------
// grid (W/16, H/4, B), 256 threads (4 waves). Tile: 4x16 = 64 px, all 256 out ch.
// Regs (64 VGPR + 64 AGPR acc) cap residency at 4 blocks/CU; LDS 34.6 KB also -> 4.
// T14 depth-1 reg pipeline, 1 barrier/chunk:
//   iter kc: { dwconv(xn[p]) -> yT[p];  ds_write regs -> xn[p^1] (chunk kc+1, loaded
//   during iter kc-1);  issue global loads chunk kc+2 -> regs;  barrier;  MFMA(yT[p]) }
// Global loads get a full chunk (~3.7k cyc >> 900 cyc HBM latency) to land, so the
// barrier no longer waits on HBM.
template<bool PREW1>
__global__ __launch_bounds__(256, 4)
void fused_mfma(const float* __restrict__ x, const float* __restrict__ lbpw,
                const float* __restrict__ w1raw, const ushort* __restrict__ w1f,
                const float* __restrict__ b1, const float* __restrict__ sc_sh,
                float* __restrict__ out) {
  const int tid  = threadIdx.x;
  const int b    = blockIdx.z;
  const int h0   = blockIdx.y * 4;
  const int w0   = blockIdx.x * 16;
  const int wave = tid >> 6;
  const int lane = tid & 63;
  const int l15  = lane & 15;
  const int quad = lane >> 4;
  const int cl   = tid >> 4;   // channel slice 0..15 (staging owner = dwconv cin)
  const int jj   = tid & 15;   // dwconv col = staging sub-index

  __shared__ float  s_scale[C_];
  __shared__ float  s_shift[C_];
  __shared__ float  s_b1[C_];
  __shared__ __align__(16) float  s_xn[2][16][6][20];   // dbuf halo tile, pitch 20
  __shared__ __align__(16) ushort s_yT[2][64][40];      // dbuf y transposed [px][o_local]
  __shared__ __align__(16) ushort s_wc[2][32][16];      // dbuf lbp weights (bf16 exact)

  s_scale[tid] = sc_sh[tid];
  s_shift[tid] = sc_sh[C_ + tid];
  s_b1[tid]    = b1[tid];

  // ---- chunk-invariant staging geometry: thread (cl,jj) owns elems jj+16k of a
  // 6x18 halo row-major slab for channel cl. Packed: bits[10:0]=LDS ofs, [28:11]=global ofs.
  int geo[7];
  unsigned actmask = 0, padmask = 0;
  #pragma unroll
  for (int k = 0; k < 7; ++k) {
    geo[k] = 0;
    const int e = jj + 16*k;
    if (e < 108) {
      const int r   = e / 18;
      const int col = e - r*18;
      const int lofs = cl*120 + r*20 + col;
      const int h = h0 + r - 1;
      const int w = w0 + col - 1;
      if (h >= 0 && h < H_ && w >= 0 && w < W_) {
        actmask |= (1u << k);
        geo[k] = ((cl*HW_ + h*W_ + w) << 11) | lofs;
      } else {
        padmask |= (1u << k);
        geo[k] = lofs;
      }
    }
  }
  // pre-zero halo-pad slots once (never touched again; valid slots rewritten each chunk)
  {
    float* p0 = &s_xn[0][0][0][0];
    float* p1 = &s_xn[1][0][0][0];
    #pragma unroll
    for (int k = 0; k < 7; ++k)
      if (padmask & (1u << k)) { p0[geo[k] & 2047] = 0.f; p1[geo[k] & 2047] = 0.f; }
  }
  // weight-staging decomposition (invariant): 32 rows x 9 taps = 288 = 256 + 32
  const int woA = tid / 9,         wjA = tid - woA*9;
  const int woB = (tid + 256) / 9, wjB = (tid + 256) - woB*9;

  f32x4 acc[4][4];
  #pragma unroll
  for (int mt = 0; mt < 4; ++mt)
    #pragma unroll
    for (int nt = 0; nt < 4; ++nt) { f32x4 z = {0.f,0.f,0.f,0.f}; acc[mt][nt] = z; }

  __syncthreads();   // scale/shift/b1 visible

  float reg[7];
  float wreg0 = 0.f, wreg1 = 0.f;

  // ---- prologue: stage chunk 0 directly; prefetch chunk 1 into regs ----
  {
    const float scl = s_scale[cl];
    const float sh  = s_shift[cl];
    const float* xc = x + (size_t)(b*C_) * HW_;
    float* xb = &s_xn[0][0][0][0];
    #pragma unroll
    for (int k = 0; k < 7; ++k)
      if (actmask & (1u << k)) xb[geo[k] & 2047] = fmaf(xc[geo[k] >> 11], scl, sh);
    s_wc[0][woA][wjA] = f2bf(lbpw[woA*9 + wjA]);
    if (tid < 32) s_wc[0][woB][wjB] = f2bf(lbpw[woB*9 + wjB]);
    // chunk-1 prefetch to regs
    const float* xc1 = xc + (size_t)16 * HW_;
    #pragma unroll
    for (int k = 0; k < 7; ++k)
      if (actmask & (1u << k)) reg[k] = xc1[geo[k] >> 11];
    wreg0 = lbpw[(32 + woA)*9 + wjA];
    if (tid < 32) wreg1 = lbpw[(32 + woB)*9 + wjB];
  }
  __syncthreads();   // xn[0], wc[0] ready

  #pragma unroll 2
  for (int kc = 0; kc < 16; ++kc) {
    const int p = kc & 1;

    // ---- A: depthwise 3x3 + relu (chunk kc) -> s_yT[p], rolling-row form ----
    {
      const uint4 qa = *(const uint4*)&s_wc[p][2*cl][0];
      const uint4 qb = *(const uint4*)&s_wc[p][2*cl + 1][0];
      const float wA[9] = { bflo(qa.x), bfhi(qa.x), bflo(qa.y), bfhi(qa.y),
                            bflo(qa.z), bfhi(qa.z), bflo(qa.w), bfhi(qa.w),
                            bf2f(s_wc[p][2*cl][8]) };
      const float wB[9] = { bflo(qb.x), bfhi(qb.x), bflo(qb.y), bfhi(qb.y),
                            bflo(qb.z), bfhi(qb.z), bflo(qb.w), bfhi(qb.w),
                            bf2f(s_wc[p][2*cl + 1][8]) };
      float a0[4] = {0.f,0.f,0.f,0.f}, a1[4] = {0.f,0.f,0.f,0.f};
      #pragma unroll
      for (int rr = 0; rr < 6; ++rr) {
        const float v0 = s_xn[p][cl][rr][jj];
        const float v1 = s_xn[p][cl][rr][jj + 1];
        const float v2 = s_xn[p][cl][rr][jj + 2];
        #pragma unroll
        for (int r = 0; r < 4; ++r) {
          const int di = rr - r;
          if (di >= 0 && di < 3) {
            a0[r] = fmaf(wA[di*3+2], v2, fmaf(wA[di*3+1], v1, fmaf(wA[di*3+0], v0, a0[r])));
            a1[r] = fmaf(wB[di*3+2], v2, fmaf(wB[di*3+1], v1, fmaf(wB[di*3+0], v0, a1[r])));
          }
        }
      }
      #pragma unroll
      for (int r = 0; r < 4; ++r) {
        const unsigned pk = (unsigned)f2bf(fmaxf(a0[r], 0.f)) |
                            ((unsigned)f2bf(fmaxf(a1[r], 0.f)) << 16);
        *(unsigned*)&s_yT[p][r*16 + jj][2*cl] = pk;
      }
    }

    // ---- B: ds_write staged regs (chunk kc+1) into buffers [p^1] ----
    if (kc < 15) {
      const int c1 = (kc + 1) * 16;
      const float scl = s_scale[c1 + cl];
      const float sh  = s_shift[c1 + cl];
      float* xb = &s_xn[p ^ 1][0][0][0];
      #pragma unroll
      for (int k = 0; k < 7; ++k)
        if (actmask & (1u << k)) xb[geo[k] & 2047] = fmaf(reg[k], scl, sh);
      s_wc[p ^ 1][woA][wjA] = f2bf(wreg0);
      if (tid < 32) s_wc[p ^ 1][woB][wjB] = f2bf(wreg1);
    }

    // ---- C: issue global loads for chunk kc+2 -> regs (a full chunk to land) ----
    if (kc < 14) {
      const float* xc = x + (size_t)(b*C_ + (kc + 2)*16) * HW_;
      #pragma unroll
      for (int k = 0; k < 7; ++k)
        if (actmask & (1u << k)) reg[k] = xc[geo[k] >> 11];
      const int o2 = (kc + 2) * 32;
      wreg0 = lbpw[(o2 + woA)*9 + wjA];
      if (tid < 32) wreg1 = lbpw[(o2 + woB)*9 + wjB];
    }

    __syncthreads();   // the ONLY barrier per chunk: yT[p] + xn/wc[p^1] ready

    // ---- D: GEMM: acc[ch][px] += w1[ch][o] * y[o][px], K=32 per chunk ----
    bf16x8 bfr[4];
    #pragma unroll
    for (int nt = 0; nt < 4; ++nt)
      bfr[nt] = *(const bf16x8*)&s_yT[p][nt*16 + l15][quad*8];

    #pragma unroll
    for (int mt = 0; mt < 4; ++mt) {
      bf16x8 afr;
      if constexpr (PREW1) {
        union { uint4 q; bf16x8 v; } cv;
        cv.q = *(const uint4*)(w1f + (size_t)(((wave*4 + mt)*16 + kc)*64 + lane)*8);
        afr = cv.v;
      } else {
        const float* wp = w1raw + (size_t)(wave*64 + mt*16 + l15)*NW_ + kc*32 + quad*8;
        const float4 f0 = *(const float4*)wp;
        const float4 f1 = *(const float4*)(wp + 4);
        union { unsigned u[4]; bf16x8 v; } cv;
        cv.u[0] = (unsigned)f2bf(f0.x) | ((unsigned)f2bf(f0.y) << 16);
        cv.u[1] = (unsigned)f2bf(f0.z) | ((unsigned)f2bf(f0.w) << 16);
        cv.u[2] = (unsigned)f2bf(f1.x) | ((unsigned)f2bf(f1.y) << 16);
        cv.u[3] = (unsigned)f2bf(f1.z) | ((unsigned)f2bf(f1.w) << 16);
        afr = cv.v;
      }
      #pragma unroll
      for (int nt = 0; nt < 4; ++nt)
        acc[mt][nt] = __builtin_amdgcn_mfma_f32_16x16x32_bf16(afr, bfr[nt], acc[mt][nt], 0, 0, 0);
    }
  }

  // ---- epilogue: + b1 + raw-x residual (exact fp32, global re-read) ----
  #pragma unroll
  for (int mt = 0; mt < 4; ++mt) {
    #pragma unroll
    for (int nt = 0; nt < 4; ++nt) {
      const int h = h0 + nt;
      #pragma unroll
      for (int i = 0; i < 4; ++i) {
        const int ch = wave*64 + mt*16 + quad*4 + i;
        const size_t o = ((size_t)(b*C_ + ch)*H_ + h)*W_ + (w0 + l15);
        out[o] = acc[mt][nt][i] + s_b1[ch] + x[o];
      }
    }
  }
}

extern "C" void kernel_launch(void* const* d_in, const int* in_sizes, int n_in,
                              void* d_out, int out_size, void* d_ws, size_t ws_size,
                              hipStream_t stream) {
  const float* x     = (const float*)d_in[0];
  const float* gamma = (const float*)d_in[1];
  const float* beta  = (const float*)d_in[2];
  const float* lbpw  = (const float*)d_in[3];
  const float* w1    = (const float*)d_in[4];
  const float* b1    = (const float*)d_in[5];
  float* out = (float*)d_out;

  // ws layout (floats): [0,256) scale | [256,512) shift | [512,2560) psum |
  //                     [2560,4608) psq | byte 18432: w1 bf16 frag table (256 KB)
  float* wsf = (float*)d_ws;
  ushort* w1f = (ushort*)((char*)d_ws + 18432);
  const bool pre = ws_size >= (size_t)(18432 + 262144);

  bn_partial<<<dim3(B_, C_), 256, 0, stream>>>(x, wsf + 512, wsf + 2560);
  bn_final<<<1, 256, 0, stream>>>(wsf, gamma, beta);

  dim3 grid(W_/16, H_/4, B_);
  if (pre) {
    w1prep<<<256, 64, 0, stream>>>(w1, w1f);
    fused_mfma<true><<<grid, 256, 0, stream>>>(x, lbpw, w1, w1f, b1, wsf, out);
  } else {
    fused_mfma<false><<<grid, 256, 0, stream>>>(x, lbpw, w1, w1f, b1, wsf, out);
  }
}

// Round 3
// 362.669 us; speedup vs baseline: 1.3458x; 1.3458x over previous
//
#include <hip/hip_runtime.h>

#define B_ 8
#define C_ 256
#define H_ 128
#define W_ 128
#define NW_ 512
#define HW_ (H_*W_)
#define EPS_ 1e-5f

typedef __attribute__((ext_vector_type(8))) short bf16x8;
typedef __attribute__((ext_vector_type(4))) float f32x4;

// RNE float -> bf16
__device__ __forceinline__ unsigned short f2bf(float f) {
  unsigned u = __float_as_uint(f);
  u += 0x7fffu + ((u >> 16) & 1u);
  return (unsigned short)(u >> 16);
}
__device__ __forceinline__ float bf2f(unsigned short h) {
  return __uint_as_float(((unsigned)h) << 16);
}
__device__ __forceinline__ float bflo(unsigned u) { return __uint_as_float(u << 16); }
__device__ __forceinline__ float bfhi(unsigned u) { return __uint_as_float(u & 0xffff0000u); }

// ---------- BN stats, two-stage ----------
__global__ __launch_bounds__(256)
void bn_partial(const float* __restrict__ x, float* __restrict__ psum,
                float* __restrict__ psq) {
  const int b = blockIdx.x, c = blockIdx.y, tid = threadIdx.x;
  const float4* p = (const float4*)(x + (size_t)(b*C_ + c) * HW_);
  float s = 0.f, s2 = 0.f;
  #pragma unroll
  for (int i = 0; i < 16; ++i) {
    float4 v = p[tid + i*256];
    s  += v.x + v.y + v.z + v.w;
    s2 += v.x*v.x + v.y*v.y + v.z*v.z + v.w*v.w;
  }
  #pragma unroll
  for (int off = 32; off > 0; off >>= 1) {
    s  += __shfl_down(s, off);
    s2 += __shfl_down(s2, off);
  }
  __shared__ float rs[4], rq[4];
  if ((tid & 63) == 0) { rs[tid >> 6] = s; rq[tid >> 6] = s2; }
  __syncthreads();
  if (tid == 0) {
    float S = rs[0]+rs[1]+rs[2]+rs[3], S2 = rq[0]+rq[1]+rq[2]+rq[3];
    psum[c*B_ + b] = S;
    psq [c*B_ + b] = S2;
  }
}

__global__ __launch_bounds__(256)
void bn_final(float* __restrict__ wsf, const float* __restrict__ gamma,
              const float* __restrict__ beta) {
  const int c = threadIdx.x;
  float S = 0.f, S2 = 0.f;
  #pragma unroll
  for (int b = 0; b < B_; ++b) { S += wsf[512 + c*B_ + b]; S2 += wsf[2560 + c*B_ + b]; }
  const float n = (float)(B_*HW_);
  float mean = S / n;
  float var  = S2 / n - mean*mean;
  float scl  = gamma[c] * rsqrtf(var + EPS_);
  wsf[c]       = scl;
  wsf[C_ + c]  = beta[c] - mean*scl;
}

// ---------- w1 -> bf16 A-fragment table ----------
__global__ __launch_bounds__(64)
void w1prep(const float* __restrict__ w1, ushort* __restrict__ w1f) {
  const int l15 = threadIdx.x & 15, quad = threadIdx.x >> 4;
  const int mtG = blockIdx.x >> 4, ks = blockIdx.x & 15;
  const float* src = w1 + (size_t)(mtG*16 + l15)*NW_ + ks*32 + quad*8;
  float4 f0 = *(const float4*)src, f1 = *(const float4*)(src + 4);
  union { unsigned u[4]; uint4 q; } cv;
  cv.u[0] = (unsigned)f2bf(f0.x) | ((unsigned)f2bf(f0.y) << 16);
  cv.u[1] = (unsigned)f2bf(f0.z) | ((unsigned)f2bf(f0.w) << 16);
  cv.u[2] = (unsigned)f2bf(f1.x) | ((unsigned)f2bf(f1.y) << 16);
  cv.u[3] = (unsigned)f2bf(f1.z) | ((unsigned)f2bf(f1.w) << 16);
  ((uint4*)w1f)[blockIdx.x*64 + threadIdx.x] = cv.q;
}

// ---------- fused: BN-apply + dw3x3 + relu + 1x1 (MFMA) + bias + residual ----------
// grid (W/16, H/4, B), 256 threads (4 waves). Tile: 4x16 = 64 px, all 256 out ch.
// __launch_bounds__(256,3): acc = 64 AGPR, leaves ~104 arch VGPR -> NO SPILL
// (round-2 lesson: (256,4) caps arch VGPR at 64; geo[] spilled -> +250 MB scratch HBM).
// Depth-1 T14 split, 1 barrier/chunk:
//   body kc: { issue w1-frag loads (chunk kc, for this MFMA);
//              issue x loads chunk kc+1 -> reg[7];
//              dwconv(xn[p]) -> yT[p]  (hides both load latencies);
//              fmaf-transform reg -> xn[p^1];
//              barrier;  MFMA(yT[p], w1q) }
// lbp weights: whole table (512x9 bf16, 12 KB) preloaded to LDS once.
template<bool PREW1>
__global__ __launch_bounds__(256, 3)
void fused_mfma(const float* __restrict__ x, const float* __restrict__ lbpw,
                const float* __restrict__ w1raw, const ushort* __restrict__ w1f,
                const float* __restrict__ b1, const float* __restrict__ sc_sh,
                float* __restrict__ out) {
  const int tid  = threadIdx.x;
  const int b    = blockIdx.z;
  const int h0   = blockIdx.y * 4;
  const int w0   = blockIdx.x * 16;
  const int wave = tid >> 6;
  const int lane = tid & 63;
  const int l15  = lane & 15;
  const int quad = lane >> 4;
  const int cl   = tid >> 4;   // channel slice 0..15 (staging owner = dwconv cin)
  const int jj   = tid & 15;   // dwconv col = staging sub-index

  __shared__ float  s_scale[C_];
  __shared__ float  s_shift[C_];
  __shared__ float  s_b1[C_];
  __shared__ __align__(16) float  s_xn[2][16][6][20];   // dbuf halo tile, pitch 20
  __shared__ __align__(16) ushort s_yT[2][64][40];      // dbuf y transposed [px][o_local]
  __shared__ __align__(8)  ushort s_wall[NW_][12];      // ALL lbp weights, bf16, pitch 12

  s_scale[tid] = sc_sh[tid];
  s_shift[tid] = sc_sh[C_ + tid];
  s_b1[tid]    = b1[tid];

  // ---- chunk-invariant staging geometry: thread (cl,jj) owns elems jj+16k of a
  // 6x18 halo row-major slab for channel cl. Packed: bits[10:0]=LDS ofs, [28:11]=global ofs.
  int geo[7];
  unsigned actmask = 0, padmask = 0;
  #pragma unroll
  for (int k = 0; k < 7; ++k) {
    geo[k] = 0;
    const int e = jj + 16*k;
    if (e < 108) {
      const int r   = e / 18;
      const int col = e - r*18;
      const int lofs = cl*120 + r*20 + col;
      const int h = h0 + r - 1;
      const int w = w0 + col - 1;
      if (h >= 0 && h < H_ && w >= 0 && w < W_) {
        actmask |= (1u << k);
        geo[k] = ((cl*HW_ + h*W_ + w) << 11) | lofs;
      } else {
        padmask |= (1u << k);
        geo[k] = lofs;
      }
    }
  }
  // pre-zero halo-pad slots once (never touched again; valid slots rewritten each chunk)
  {
    float* p0 = &s_xn[0][0][0][0];
    float* p1 = &s_xn[1][0][0][0];
    #pragma unroll
    for (int k = 0; k < 7; ++k)
      if (padmask & (1u << k)) { p0[geo[k] & 2047] = 0.f; p1[geo[k] & 2047] = 0.f; }
  }

  f32x4 acc[4][4];
  #pragma unroll
  for (int mt = 0; mt < 4; ++mt)
    #pragma unroll
    for (int nt = 0; nt < 4; ++nt) { f32x4 z = {0.f,0.f,0.f,0.f}; acc[mt][nt] = z; }

  __syncthreads();   // scale/shift/b1 visible

  // ---- one-time: whole lbp-weight table -> LDS (bf16 exact for {-1,0,1}) ----
  #pragma unroll
  for (int rr = 0; rr < 2; ++rr) {
    const int row = tid + rr*256;
    const float* wp = lbpw + (size_t)row*9;
    #pragma unroll
    for (int j = 0; j < 9; ++j) s_wall[row][j] = f2bf(wp[j]);
  }
  // ---- prologue: stage chunk 0 into buffer 0 (serial latency once) ----
  {
    const float scl = s_scale[cl];
    const float sh  = s_shift[cl];
    const float* xc = x + (size_t)(b*C_) * HW_;
    float* xb = &s_xn[0][0][0][0];
    #pragma unroll
    for (int k = 0; k < 7; ++k)
      if (actmask & (1u << k)) xb[geo[k] & 2047] = fmaf(xc[geo[k] >> 11], scl, sh);
  }
  __syncthreads();   // xn[0] + s_wall ready

  #pragma unroll 2
  for (int kc = 0; kc < 16; ++kc) {
    const int p = kc & 1;

    // ---- A: issue w1 fragment loads for THIS chunk's MFMA (hide L2 latency) ----
    uint4 w1q[4];
    if constexpr (PREW1) {
      #pragma unroll
      for (int mt = 0; mt < 4; ++mt)
        w1q[mt] = *(const uint4*)(w1f + (size_t)(((wave*4 + mt)*16 + kc)*64 + lane)*8);
    }

    // ---- B: issue x loads for chunk kc+1 (consumed at D; dwconv hides HBM latency) ----
    float reg[7];
    if (kc < 15) {
      const float* xc = x + (size_t)(b*C_ + (kc + 1)*16) * HW_;
      #pragma unroll
      for (int k = 0; k < 7; ++k)
        if (actmask & (1u << k)) reg[k] = xc[geo[k] >> 11];
    }

    // ---- C: depthwise 3x3 + relu (chunk kc) -> s_yT[p], rolling-row form ----
    {
      const ushort* wr0 = &s_wall[kc*32 + 2*cl][0];
      const ushort* wr1 = &s_wall[kc*32 + 2*cl + 1][0];
      const uint2 qa0 = *(const uint2*)(wr0);
      const uint2 qa1 = *(const uint2*)(wr0 + 4);
      const unsigned qa2 = *(const unsigned*)(wr0 + 8);
      const uint2 qb0 = *(const uint2*)(wr1);
      const uint2 qb1 = *(const uint2*)(wr1 + 4);
      const unsigned qb2 = *(const unsigned*)(wr1 + 8);
      const float wA[9] = { bflo(qa0.x), bfhi(qa0.x), bflo(qa0.y), bfhi(qa0.y),
                            bflo(qa1.x), bfhi(qa1.x), bflo(qa1.y), bfhi(qa1.y),
                            bflo(qa2) };
      const float wB[9] = { bflo(qb0.x), bfhi(qb0.x), bflo(qb0.y), bfhi(qb0.y),
                            bflo(qb1.x), bfhi(qb1.x), bflo(qb1.y), bfhi(qb1.y),
                            bflo(qb2) };
      float a0[4] = {0.f,0.f,0.f,0.f}, a1[4] = {0.f,0.f,0.f,0.f};
      #pragma unroll
      for (int rr = 0; rr < 6; ++rr) {
        const float v0 = s_xn[p][cl][rr][jj];
        const float v1 = s_xn[p][cl][rr][jj + 1];
        const float v2 = s_xn[p][cl][rr][jj + 2];
        #pragma unroll
        for (int r = 0; r < 4; ++r) {
          const int di = rr - r;
          if (di >= 0 && di < 3) {
            a0[r] = fmaf(wA[di*3+2], v2, fmaf(wA[di*3+1], v1, fmaf(wA[di*3+0], v0, a0[r])));
            a1[r] = fmaf(wB[di*3+2], v2, fmaf(wB[di*3+1], v1, fmaf(wB[di*3+0], v0, a1[r])));
          }
        }
      }
      #pragma unroll
      for (int r = 0; r < 4; ++r) {
        const unsigned pk = (unsigned)f2bf(fmaxf(a0[r], 0.f)) |
                            ((unsigned)f2bf(fmaxf(a1[r], 0.f)) << 16);
        *(unsigned*)&s_yT[p][r*16 + jj][2*cl] = pk;
      }
    }

    // ---- D: transform staged regs (chunk kc+1) -> xn[p^1] ----
    if (kc < 15) {
      const int c1 = (kc + 1) * 16 + cl;
      const float scl = s_scale[c1];
      const float sh  = s_shift[c1];
      float* xb = &s_xn[p ^ 1][0][0][0];
      #pragma unroll
      for (int k = 0; k < 7; ++k)
        if (actmask & (1u << k)) xb[geo[k] & 2047] = fmaf(reg[k], scl, sh);
    }

    __syncthreads();   // the ONLY barrier per chunk: yT[p] + xn[p^1] ready

    // ---- E: GEMM: acc[ch][px] += w1[ch][o] * y[o][px], K=32 per chunk ----
    bf16x8 bfr[4];
    #pragma unroll
    for (int nt = 0; nt < 4; ++nt)
      bfr[nt] = *(const bf16x8*)&s_yT[p][nt*16 + l15][quad*8];

    #pragma unroll
    for (int mt = 0; mt < 4; ++mt) {
      bf16x8 afr;
      if constexpr (PREW1) {
        union { uint4 q; bf16x8 v; } cv;
        cv.q = w1q[mt];
        afr = cv.v;
      } else {
        const float* wp = w1raw + (size_t)(wave*64 + mt*16 + l15)*NW_ + kc*32 + quad*8;
        const float4 f0 = *(const float4*)wp;
        const float4 f1 = *(const float4*)(wp + 4);
        union { unsigned u[4]; bf16x8 v; } cv;
        cv.u[0] = (unsigned)f2bf(f0.x) | ((unsigned)f2bf(f0.y) << 16);
        cv.u[1] = (unsigned)f2bf(f0.z) | ((unsigned)f2bf(f0.w) << 16);
        cv.u[2] = (unsigned)f2bf(f1.x) | ((unsigned)f2bf(f1.y) << 16);
        cv.u[3] = (unsigned)f2bf(f1.z) | ((unsigned)f2bf(f1.w) << 16);
        afr = cv.v;
      }
      #pragma unroll
      for (int nt = 0; nt < 4; ++nt)
        acc[mt][nt] = __builtin_amdgcn_mfma_f32_16x16x32_bf16(afr, bfr[nt], acc[mt][nt], 0, 0, 0);
    }
  }

  // ---- epilogue: + b1 + raw-x residual (exact fp32, global re-read) ----
  #pragma unroll
  for (int mt = 0; mt < 4; ++mt) {
    #pragma unroll
    for (int nt = 0; nt < 4; ++nt) {
      const int h = h0 + nt;
      #pragma unroll
      for (int i = 0; i < 4; ++i) {
        const int ch = wave*64 + mt*16 + quad*4 + i;
        const size_t o = ((size_t)(b*C_ + ch)*H_ + h)*W_ + (w0 + l15);
        out[o] = acc[mt][nt][i] + s_b1[ch] + x[o];
      }
    }
  }
}

extern "C" void kernel_launch(void* const* d_in, const int* in_sizes, int n_in,
                              void* d_out, int out_size, void* d_ws, size_t ws_size,
                              hipStream_t stream) {
  const float* x     = (const float*)d_in[0];
  const float* gamma = (const float*)d_in[1];
  const float* beta  = (const float*)d_in[2];
  const float* lbpw  = (const float*)d_in[3];
  const float* w1    = (const float*)d_in[4];
  const float* b1    = (const float*)d_in[5];
  float* out = (float*)d_out;

  // ws layout (floats): [0,256) scale | [256,512) shift | [512,2560) psum |
  //                     [2560,4608) psq | byte 18432: w1 bf16 frag table (256 KB)
  float* wsf = (float*)d_ws;
  ushort* w1f = (ushort*)((char*)d_ws + 18432);
  const bool pre = ws_size >= (size_t)(18432 + 262144);

  bn_partial<<<dim3(B_, C_), 256, 0, stream>>>(x, wsf + 512, wsf + 2560);
  bn_final<<<1, 256, 0, stream>>>(wsf, gamma, beta);

  dim3 grid(W_/16, H_/4, B_);
  if (pre) {
    w1prep<<<256, 64, 0, stream>>>(w1, w1f);
    fused_mfma<true><<<grid, 256, 0, stream>>>(x, lbpw, w1, w1f, b1, wsf, out);
  } else {
    fused_mfma<false><<<grid, 256, 0, stream>>>(x, lbpw, w1, w1f, b1, wsf, out);
  }
}

// Round 4
// 358.091 us; speedup vs baseline: 1.3630x; 1.0128x over previous
//
#include <hip/hip_runtime.h>

#define B_ 8
#define C_ 256
#define H_ 128
#define W_ 128
#define NW_ 512
#define HW_ (H_*W_)
#define EPS_ 1e-5f

typedef __attribute__((ext_vector_type(8))) short bf16x8;
typedef __attribute__((ext_vector_type(4))) float f32x4;

// RNE float -> bf16
__device__ __forceinline__ unsigned short f2bf(float f) {
  unsigned u = __float_as_uint(f);
  u += 0x7fffu + ((u >> 16) & 1u);
  return (unsigned short)(u >> 16);
}
__device__ __forceinline__ float bf2f(unsigned short h) {
  return __uint_as_float(((unsigned)h) << 16);
}
__device__ __forceinline__ float bflo(unsigned u) { return __uint_as_float(u << 16); }
__device__ __forceinline__ float bfhi(unsigned u) { return __uint_as_float(u & 0xffff0000u); }

// ---------- BN stats, two-stage ----------
__global__ __launch_bounds__(256)
void bn_partial(const float* __restrict__ x, float* __restrict__ psum,
                float* __restrict__ psq) {
  const int b = blockIdx.x, c = blockIdx.y, tid = threadIdx.x;
  const float4* p = (const float4*)(x + (size_t)(b*C_ + c) * HW_);
  float s = 0.f, s2 = 0.f;
  #pragma unroll
  for (int i = 0; i < 16; ++i) {
    float4 v = p[tid + i*256];
    s  += v.x + v.y + v.z + v.w;
    s2 += v.x*v.x + v.y*v.y + v.z*v.z + v.w*v.w;
  }
  #pragma unroll
  for (int off = 32; off > 0; off >>= 1) {
    s  += __shfl_down(s, off);
    s2 += __shfl_down(s2, off);
  }
  __shared__ float rs[4], rq[4];
  if ((tid & 63) == 0) { rs[tid >> 6] = s; rq[tid >> 6] = s2; }
  __syncthreads();
  if (tid == 0) {
    float S = rs[0]+rs[1]+rs[2]+rs[3], S2 = rq[0]+rq[1]+rq[2]+rq[3];
    psum[c*B_ + b] = S;
    psq [c*B_ + b] = S2;
  }
}

__global__ __launch_bounds__(256)
void bn_final(float* __restrict__ wsf, const float* __restrict__ gamma,
              const float* __restrict__ beta) {
  const int c = threadIdx.x;
  float S = 0.f, S2 = 0.f;
  #pragma unroll
  for (int b = 0; b < B_; ++b) { S += wsf[512 + c*B_ + b]; S2 += wsf[2560 + c*B_ + b]; }
  const float n = (float)(B_*HW_);
  float mean = S / n;
  float var  = S2 / n - mean*mean;
  float scl  = gamma[c] * rsqrtf(var + EPS_);
  wsf[c]       = scl;
  wsf[C_ + c]  = beta[c] - mean*scl;
}

// ---------- w1 -> bf16 A-fragment table ----------
__global__ __launch_bounds__(64)
void w1prep(const float* __restrict__ w1, ushort* __restrict__ w1f) {
  const int l15 = threadIdx.x & 15, quad = threadIdx.x >> 4;
  const int mtG = blockIdx.x >> 4, ks = blockIdx.x & 15;
  const float* src = w1 + (size_t)(mtG*16 + l15)*NW_ + ks*32 + quad*8;
  float4 f0 = *(const float4*)src, f1 = *(const float4*)(src + 4);
  union { unsigned u[4]; uint4 q; } cv;
  cv.u[0] = (unsigned)f2bf(f0.x) | ((unsigned)f2bf(f0.y) << 16);
  cv.u[1] = (unsigned)f2bf(f0.z) | ((unsigned)f2bf(f0.w) << 16);
  cv.u[2] = (unsigned)f2bf(f1.x) | ((unsigned)f2bf(f1.y) << 16);
  cv.u[3] = (unsigned)f2bf(f1.z) | ((unsigned)f2bf(f1.w) << 16);
  ((uint4*)w1f)[blockIdx.x*64 + threadIdx.x] = cv.q;
}

// ---------- fused: BN-apply + dw3x3 + relu + 1x1 (MFMA) + bias + residual ----------
// grid (W/16, H/4, B), 256 threads (4 waves). Tile: 4x16 = 64 px, all 256 out ch.
// __launch_bounds__(256,3): ~104 arch VGPR headroom after 64 AGPR acc -> no spill.
// Round-4 change: staging stream vectorized. Halo slab rows are pitch-24 floats:
//   cols 0..2 pad | col 3 = w0-1 | cols 4..19 = w0..w0+15 (float4-aligned!) | col 20 = w0+16.
// Interior loads = global_load_dwordx4 (384 slots, <=2/thread), halo = scalar (192 slots).
// 4.5x bytes-in-flight on the dominant HBM stream vs 7 scalar loads/thread.
// Depth-1 T14 split, 1 barrier/chunk:
//   body kc: { issue w1-frag loads (chunk kc); issue x loads chunk kc+1 -> regs;
//              dwconv(xn[p]) -> yT[p] (hides latency); fmaf regs -> xn[p^1];
//              barrier; MFMA(yT[p], w1q) }
template<bool PREW1>
__global__ __launch_bounds__(256, 3)
void fused_mfma(const float* __restrict__ x, const float* __restrict__ lbpw,
                const float* __restrict__ w1raw, const ushort* __restrict__ w1f,
                const float* __restrict__ b1, const float* __restrict__ sc_sh,
                float* __restrict__ out) {
  const int tid  = threadIdx.x;
  const int b    = blockIdx.z;
  const int h0   = blockIdx.y * 4;
  const int w0   = blockIdx.x * 16;
  const int wave = tid >> 6;
  const int lane = tid & 63;
  const int l15  = lane & 15;
  const int quad = lane >> 4;
  const int cl   = tid >> 4;   // dwconv: channel slice 0..15
  const int jj   = tid & 15;   // dwconv: output column 0..15

  __shared__ float  s_scale[C_];
  __shared__ float  s_shift[C_];
  __shared__ float  s_b1[C_];
  __shared__ __align__(16) float  s_xn[2][16][6][24];   // dbuf halo tile, pitch 24
  __shared__ __align__(16) ushort s_yT[2][64][40];      // dbuf y transposed [px][o_local]
  __shared__ __align__(8)  ushort s_wall[NW_][12];      // ALL lbp weights, bf16, pitch 12

  s_scale[tid] = sc_sh[tid];
  s_shift[tid] = sc_sh[C_ + tid];
  s_b1[tid]    = b1[tid];

  // ---- chunk-invariant staging geometry ----
  // interior slot s (0..383): ch=s/24, r=(s%24)>>2, q=(s%24)&3
  //   lofs = ch*144 + r*24 + 4 + q*4 (floats), g = ch*HW + (h0+r-1)*W + w0 + q*4
  // halo slot s (0..191): ch=s/12, r=(s%12)>>1, side=(s%12)&1
  //   lofs = ch*144 + r*24 + (side?20:3), g = ch*HW + (h0+r-1)*W + w0 + (side?16:-1)
  int lA, gA = 0, cA, vA = 0;
  {
    const int s = tid, ch = s/24, rem = s - ch*24, r = rem >> 2, q = rem & 3;
    cA = ch; lA = ch*144 + r*24 + 4 + q*4;
    const int h = h0 + r - 1;
    if (h >= 0 && h < H_) { vA = 1; gA = ch*HW_ + h*W_ + w0 + q*4; }
  }
  const int hasB = (tid < 128);
  int lB = 0, gB = 0, cB = 0, vB = 0;
  if (hasB) {
    const int s = tid + 256, ch = s/24, rem = s - ch*24, r = rem >> 2, q = rem & 3;
    cB = ch; lB = ch*144 + r*24 + 4 + q*4;
    const int h = h0 + r - 1;
    if (h >= 0 && h < H_) { vB = 1; gB = ch*HW_ + h*W_ + w0 + q*4; }
  }
  const int hasH = (tid < 192);
  int lH = 0, gH = 0, cH = 0, vH = 0;
  if (hasH) {
    const int s = tid, ch = s/12, rem = s - ch*12, r = rem >> 1, side = rem & 1;
    cH = ch; lH = ch*144 + r*24 + (side ? 20 : 3);
    const int h = h0 + r - 1;
    const int w = w0 + (side ? 16 : -1);
    if (h >= 0 && h < H_ && w >= 0 && w < W_) { vH = 1; gH = ch*HW_ + h*W_ + w; }
  }
  // pre-zero pad slots once (valid slots are rewritten every chunk)
  {
    float* z0 = &s_xn[0][0][0][0];
    float* z1 = &s_xn[1][0][0][0];
    const float4 z4 = {0.f, 0.f, 0.f, 0.f};
    if (!vA)          { *(float4*)(z0 + lA) = z4; *(float4*)(z1 + lA) = z4; }
    if (hasB && !vB)  { *(float4*)(z0 + lB) = z4; *(float4*)(z1 + lB) = z4; }
    if (hasH && !vH)  { z0[lH] = 0.f; z1[lH] = 0.f; }
  }

  f32x4 acc[4][4];
  #pragma unroll
  for (int mt = 0; mt < 4; ++mt)
    #pragma unroll
    for (int nt = 0; nt < 4; ++nt) { f32x4 z = {0.f,0.f,0.f,0.f}; acc[mt][nt] = z; }

  __syncthreads();   // scale/shift/b1 visible

  // ---- one-time: whole lbp-weight table -> LDS (bf16 exact for {-1,0,1}) ----
  #pragma unroll
  for (int rr = 0; rr < 2; ++rr) {
    const int row = tid + rr*256;
    const float* wp = lbpw + (size_t)row*9;
    #pragma unroll
    for (int j = 0; j < 9; ++j) s_wall[row][j] = f2bf(wp[j]);
  }
  // ---- prologue: stage chunk 0 into buffer 0 ----
  {
    const float* xc = x + (size_t)(b*C_) * HW_;
    float* xb = &s_xn[0][0][0][0];
    if (vA) {
      const float4 t = *(const float4*)(xc + gA);
      const float sc = s_scale[cA], sh = s_shift[cA];
      float4 o; o.x = fmaf(t.x, sc, sh); o.y = fmaf(t.y, sc, sh);
                o.z = fmaf(t.z, sc, sh); o.w = fmaf(t.w, sc, sh);
      *(float4*)(xb + lA) = o;
    }
    if (vB) {
      const float4 t = *(const float4*)(xc + gB);
      const float sc = s_scale[cB], sh = s_shift[cB];
      float4 o; o.x = fmaf(t.x, sc, sh); o.y = fmaf(t.y, sc, sh);
                o.z = fmaf(t.z, sc, sh); o.w = fmaf(t.w, sc, sh);
      *(float4*)(xb + lB) = o;
    }
    if (vH) xb[lH] = fmaf(xc[gH], s_scale[cH], s_shift[cH]);
  }
  __syncthreads();   // xn[0] + s_wall ready

  #pragma unroll 2
  for (int kc = 0; kc < 16; ++kc) {
    const int p = kc & 1;

    // ---- A: issue w1 fragment loads for THIS chunk's MFMA (hide L2 latency) ----
    uint4 w1q[4];
    if constexpr (PREW1) {
      #pragma unroll
      for (int mt = 0; mt < 4; ++mt)
        w1q[mt] = *(const uint4*)(w1f + (size_t)(((wave*4 + mt)*16 + kc)*64 + lane)*8);
    }

    // ---- B: issue x loads for chunk kc+1 (vectorized; consumed at D) ----
    float4 rgA, rgB; float rgH;
    if (kc < 15) {
      const float* xc = x + (size_t)(b*C_ + (kc + 1)*16) * HW_;
      if (vA) rgA = *(const float4*)(xc + gA);
      if (vB) rgB = *(const float4*)(xc + gB);
      if (vH) rgH = xc[gH];
    }

    // ---- C: depthwise 3x3 + relu (chunk kc) -> s_yT[p], rolling-row form ----
    {
      const ushort* wr0 = &s_wall[kc*32 + 2*cl][0];
      const ushort* wr1 = &s_wall[kc*32 + 2*cl + 1][0];
      const uint2 qa0 = *(const uint2*)(wr0);
      const uint2 qa1 = *(const uint2*)(wr0 + 4);
      const unsigned qa2 = *(const unsigned*)(wr0 + 8);
      const uint2 qb0 = *(const uint2*)(wr1);
      const uint2 qb1 = *(const uint2*)(wr1 + 4);
      const unsigned qb2 = *(const unsigned*)(wr1 + 8);
      const float wA[9] = { bflo(qa0.x), bfhi(qa0.x), bflo(qa0.y), bfhi(qa0.y),
                            bflo(qa1.x), bfhi(qa1.x), bflo(qa1.y), bfhi(qa1.y),
                            bflo(qa2) };
      const float wB[9] = { bflo(qb0.x), bfhi(qb0.x), bflo(qb0.y), bfhi(qb0.y),
                            bflo(qb1.x), bfhi(qb1.x), bflo(qb1.y), bfhi(qb1.y),
                            bflo(qb2) };
      float a0[4] = {0.f,0.f,0.f,0.f}, a1[4] = {0.f,0.f,0.f,0.f};
      #pragma unroll
      for (int rr = 0; rr < 6; ++rr) {
        const float v0 = s_xn[p][cl][rr][3 + jj];
        const float v1 = s_xn[p][cl][rr][4 + jj];
        const float v2 = s_xn[p][cl][rr][5 + jj];
        #pragma unroll
        for (int r = 0; r < 4; ++r) {
          const int di = rr - r;
          if (di >= 0 && di < 3) {
            a0[r] = fmaf(wA[di*3+2], v2, fmaf(wA[di*3+1], v1, fmaf(wA[di*3+0], v0, a0[r])));
            a1[r] = fmaf(wB[di*3+2], v2, fmaf(wB[di*3+1], v1, fmaf(wB[di*3+0], v0, a1[r])));
          }
        }
      }
      #pragma unroll
      for (int r = 0; r < 4; ++r) {
        const unsigned pk = (unsigned)f2bf(fmaxf(a0[r], 0.f)) |
                            ((unsigned)f2bf(fmaxf(a1[r], 0.f)) << 16);
        *(unsigned*)&s_yT[p][r*16 + jj][2*cl] = pk;
      }
    }

    // ---- D: transform staged regs (chunk kc+1) -> xn[p^1] ----
    if (kc < 15) {
      const int c1 = (kc + 1) * 16;
      float* xb = &s_xn[p ^ 1][0][0][0];
      if (vA) {
        const float sc = s_scale[c1 + cA], sh = s_shift[c1 + cA];
        float4 o; o.x = fmaf(rgA.x, sc, sh); o.y = fmaf(rgA.y, sc, sh);
                  o.z = fmaf(rgA.z, sc, sh); o.w = fmaf(rgA.w, sc, sh);
        *(float4*)(xb + lA) = o;
      }
      if (vB) {
        const float sc = s_scale[c1 + cB], sh = s_shift[c1 + cB];
        float4 o; o.x = fmaf(rgB.x, sc, sh); o.y = fmaf(rgB.y, sc, sh);
                  o.z = fmaf(rgB.z, sc, sh); o.w = fmaf(rgB.w, sc, sh);
        *(float4*)(xb + lB) = o;
      }
      if (vH) xb[lH] = fmaf(rgH, s_scale[c1 + cH], s_shift[c1 + cH]);
    }

    __syncthreads();   // the ONLY barrier per chunk: yT[p] + xn[p^1] ready

    // ---- E: GEMM: acc[ch][px] += w1[ch][o] * y[o][px], K=32 per chunk ----
    bf16x8 bfr[4];
    #pragma unroll
    for (int nt = 0; nt < 4; ++nt)
      bfr[nt] = *(const bf16x8*)&s_yT[p][nt*16 + l15][quad*8];

    #pragma unroll
    for (int mt = 0; mt < 4; ++mt) {
      bf16x8 afr;
      if constexpr (PREW1) {
        union { uint4 q; bf16x8 v; } cv;
        cv.q = w1q[mt];
        afr = cv.v;
      } else {
        const float* wp = w1raw + (size_t)(wave*64 + mt*16 + l15)*NW_ + kc*32 + quad*8;
        const float4 f0 = *(const float4*)wp;
        const float4 f1 = *(const float4*)(wp + 4);
        union { unsigned u[4]; bf16x8 v; } cv;
        cv.u[0] = (unsigned)f2bf(f0.x) | ((unsigned)f2bf(f0.y) << 16);
        cv.u[1] = (unsigned)f2bf(f0.z) | ((unsigned)f2bf(f0.w) << 16);
        cv.u[2] = (unsigned)f2bf(f1.x) | ((unsigned)f2bf(f1.y) << 16);
        cv.u[3] = (unsigned)f2bf(f1.z) | ((unsigned)f2bf(f1.w) << 16);
        afr = cv.v;
      }
      #pragma unroll
      for (int nt = 0; nt < 4; ++nt)
        acc[mt][nt] = __builtin_amdgcn_mfma_f32_16x16x32_bf16(afr, bfr[nt], acc[mt][nt], 0, 0, 0);
    }
  }

  // ---- epilogue: + b1 + raw-x residual (exact fp32, global re-read) ----
  #pragma unroll
  for (int mt = 0; mt < 4; ++mt) {
    #pragma unroll
    for (int nt = 0; nt < 4; ++nt) {
      const int h = h0 + nt;
      #pragma unroll
      for (int i = 0; i < 4; ++i) {
        const int ch = wave*64 + mt*16 + quad*4 + i;
        const size_t o = ((size_t)(b*C_ + ch)*H_ + h)*W_ + (w0 + l15);
        out[o] = acc[mt][nt][i] + s_b1[ch] + x[o];
      }
    }
  }
}

extern "C" void kernel_launch(void* const* d_in, const int* in_sizes, int n_in,
                              void* d_out, int out_size, void* d_ws, size_t ws_size,
                              hipStream_t stream) {
  const float* x     = (const float*)d_in[0];
  const float* gamma = (const float*)d_in[1];
  const float* beta  = (const float*)d_in[2];
  const float* lbpw  = (const float*)d_in[3];
  const float* w1    = (const float*)d_in[4];
  const float* b1    = (const float*)d_in[5];
  float* out = (float*)d_out;

  // ws layout (floats): [0,256) scale | [256,512) shift | [512,2560) psum |
  //                     [2560,4608) psq | byte 18432: w1 bf16 frag table (256 KB)
  float* wsf = (float*)d_ws;
  ushort* w1f = (ushort*)((char*)d_ws + 18432);
  const bool pre = ws_size >= (size_t)(18432 + 262144);

  bn_partial<<<dim3(B_, C_), 256, 0, stream>>>(x, wsf + 512, wsf + 2560);
  bn_final<<<1, 256, 0, stream>>>(wsf, gamma, beta);

  dim3 grid(W_/16, H_/4, B_);
  if (pre) {
    w1prep<<<256, 64, 0, stream>>>(w1, w1f);
    fused_mfma<true><<<grid, 256, 0, stream>>>(x, lbpw, w1, w1f, b1, wsf, out);
  } else {
    fused_mfma<false><<<grid, 256, 0, stream>>>(x, lbpw, w1, w1f, b1, wsf, out);
  }
}